// Round 7
// baseline (1188.904 us; speedup 1.0000x reference)
//
#include <hip/hip_runtime.h>

#define B_TOT 262144
#define HID   256
#define NHEAD 8
#define BR    128      // rows per block
#define NTHR  512      // 8 waves; wave owns 16 batch rows end-to-end

typedef __bf16 bf16_t;
typedef __attribute__((ext_vector_type(8))) __bf16 bf16x8;
typedef __attribute__((ext_vector_type(4))) __bf16 bf16x4;
typedef __attribute__((ext_vector_type(4))) float  f32x4;

// d_ws layout (bf16, fragment-ordered; byte = chunk*1024 + lane*16):
//   QKV: chunk = (h*8+ks)*6 + wi*2 + half   (wi: 0=q 1=k 2=v), chunk in [0,384)
//        element = W[h*32 + PI(lane&15,half)][ks*32 + (lane>>4)*8 .. +8]
//        PI(m,half) = (m>>2)*8 + half*4 + (m&3)
//        (permutation makes attention-mix C-frags == out-proj B-frags, no shuffles)
//   Wo:  chunk = 384 + ks*16 + jt, chunk in [384,512)
//        element = Wo[jt*16 + (lane&15)][ks*32 + (lane>>4)*8 .. +8]   (linear cols)
#define QKV_BYTES (384 * 1024)

static __device__ __forceinline__ f32x4 mfma16(bf16x8 a, bf16x8 b, f32x4 c) {
  return __builtin_amdgcn_mfma_f32_16x16x32_bf16(a, b, c, 0, 0, 0);
}

static __device__ __forceinline__ bf16x8 cvt8(float4 a, float4 b) {
  bf16x8 r;
  r[0] = (bf16_t)a.x; r[1] = (bf16_t)a.y; r[2] = (bf16_t)a.z; r[3] = (bf16_t)a.w;
  r[4] = (bf16_t)b.x; r[5] = (bf16_t)b.y; r[6] = (bf16_t)b.z; r[7] = (bf16_t)b.w;
  return r;
}

// opaque register pin: forbids rematerialization of the producing loads
static __device__ __forceinline__ bf16x8 pin8(bf16x8 v) {
  f32x4 t = __builtin_bit_cast(f32x4, v);
  asm volatile("" : "+v"(t));
  return __builtin_bit_cast(bf16x8, t);
}

// async global -> LDS, 16B per lane; lds dest must be linear (uniform base + lane*16)
typedef __attribute__((address_space(3))) void lds_void;
typedef __attribute__((address_space(1))) void gbl_void;
static __device__ __forceinline__ void gload_lds16(const void* g, void* l) {
  __builtin_amdgcn_global_load_lds((gbl_void*)g, (lds_void*)l, 16, 0, 0);
}

// ---- one-shot weight pack: f32 row-major -> bf16 fragment-ordered in ws ----
__global__ __launch_bounds__(256) void pack_weights(
    const float* __restrict__ Wq, const float* __restrict__ Wk,
    const float* __restrict__ Wv, const float* __restrict__ Wo,
    bf16_t* __restrict__ ws) {
  const int t     = blockIdx.x * 256 + threadIdx.x;   // 0..32767
  const int lane  = t & 63;
  const int chunk = t >> 6;                           // 0..511
  const int l15 = lane & 15, lg = lane >> 4;
  const float* src;
  int row, col;
  if (chunk < 384) {  // QKV: 64 (h,ks) pairs * 6 slots
    const int slot = chunk % 6;          // wi*2 + half
    const int hk   = chunk / 6;          // h*8 + ks
    const int wi = slot >> 1, half = slot & 1;
    const int h = hk >> 3, ks = hk & 7;
    src = (wi == 0) ? Wq : (wi == 1) ? Wk : Wv;
    row = h * 32 + (l15 >> 2) * 8 + half * 4 + (l15 & 3);   // PI permutation
    col = ks * 32 + lg * 8;
  } else {            // Wo: 8 ks * 16 jt, linear
    const int c  = chunk - 384;
    const int ks = c >> 4, jt = c & 15;
    src = Wo;
    row = jt * 16 + l15;
    col = ks * 32 + lg * 8;
  }
  const float* p = src + (size_t)row * HID + col;
  const float4 a = *(const float4*)p;
  const float4 b = *(const float4*)(p + 4);
  *(bf16x8*)(ws + (size_t)t * 8) = cvt8(a, b);
}

__global__ __launch_bounds__(NTHR, 6) void fused_local_aug(
    const float* __restrict__ fine, const float* __restrict__ coarse,
    const float* __restrict__ motif, const bf16_t* __restrict__ wpk,
    const float* __restrict__ bo, float* __restrict__ out) {
  // double-buffered W staging: 2 x 24 KB -> 48 KB total -> 3 blocks/CU
  __shared__ char wbuf[49152];

  const int tid  = threadIdx.x;
  const int lane = tid & 63;
  const int wave = tid >> 6;        // 0..7
  const int l15  = lane & 15;
  const int lg   = lane >> 4;       // 0..3
  const size_t row0 = (size_t)blockIdx.x * BR;
  const size_t mrow = row0 + wave * 16 + l15;   // this lane's batch row

  // phase table: ph 0..15 = (head h=ph>>1, half=ph&1), 24 KB each
  //              ph 16..23 = Wo ks-slot (ph-16), 16 KB each
  // phase ph reads wbuf[(ph&1)*24576]; stage(ph) writes the same.
  auto stage = [&](int ph) {
    if (ph >= 24) return;
    char* dst = wbuf + (ph & 1) * 24576 + tid * 16;
    if (ph < 16) {
      const char* src = (const char*)wpk + (ph >> 1) * 49152 + (ph & 1) * 24576 + tid * 16;
      gload_lds16(src, dst);
      gload_lds16(src + 8192, dst + 8192);
      gload_lds16(src + 16384, dst + 16384);
    } else {
      const char* src = (const char*)wpk + QKV_BYTES + (ph - 16) * 16384 + tid * 16;
      gload_lds16(src, dst);
      gload_lds16(src + 8192, dst + 8192);
    }
  };

  stage(0);   // prefetch phase 0 under the X prologue

  // ---- preload this wave's 16 X rows into pinned bf16 register fragments ----
  bf16x8 xm[8], xf[8], xc[8];
  {
    const float* pm = motif  + mrow * HID + lg * 8;
    const float* pf = fine   + mrow * HID + lg * 8;
    const float* pc = coarse + mrow * HID + lg * 8;
#pragma unroll
    for (int s = 0; s < 8; ++s) {
      xm[s] = pin8(cvt8(*(const float4*)(pm + s * 32), *(const float4*)(pm + s * 32 + 4)));
      xf[s] = pin8(cvt8(*(const float4*)(pf + s * 32), *(const float4*)(pf + s * 32 + 4)));
      xc[s] = pin8(cvt8(*(const float4*)(pc + s * 32), *(const float4*)(pc + s * 32 + 4)));
    }
  }
  __syncthreads();   // phase 0 staged (vmcnt drained by all waves + barrier)

  // mid kept in registers: mo0[h][r] = feature h*32+lg*8+r, mo1[h][r] = +4
  bf16x4 mo0[NHEAD], mo1[NHEAD];

  // ---- head loop: 2 pipelined sub-phases per head, ONE barrier per phase ----
#pragma unroll
  for (int h = 0; h < NHEAD; ++h) {
    f32x4 aQ0{}, aQ1{}, aK10{}, aK11{}, aK20{}, aK21{}, aV10{}, aV11{}, aV20{}, aV21{};
#pragma unroll
    for (int half = 0; half < 2; ++half) {
      stage(2 * h + half + 1);               // issue next phase's loads FIRST
      const char* pb = wbuf + ((2 * h + half) & 1) * 24576 + lane * 16;
#pragma unroll
      for (int kk = 0; kk < 4; ++kk) {       // compute current buffer
        const int ks = half * 4 + kk;
        const char* p = pb + kk * 6144;
        bf16x8 q0 = *(const bf16x8*)(p);
        bf16x8 q1 = *(const bf16x8*)(p + 1024);
        bf16x8 k0 = *(const bf16x8*)(p + 2048);
        bf16x8 k1 = *(const bf16x8*)(p + 3072);
        bf16x8 v0 = *(const bf16x8*)(p + 4096);
        bf16x8 v1 = *(const bf16x8*)(p + 5120);
        aQ0  = mfma16(q0, xm[ks], aQ0);   aQ1  = mfma16(q1, xm[ks], aQ1);
        aK10 = mfma16(k0, xf[ks], aK10);  aK11 = mfma16(k1, xf[ks], aK11);
        aK20 = mfma16(k0, xc[ks], aK20);  aK21 = mfma16(k1, xc[ks], aK21);
        aV10 = mfma16(v0, xf[ks], aV10);  aV11 = mfma16(v1, xf[ks], aV11);
        aV20 = mfma16(v0, xc[ks], aV20);  aV21 = mfma16(v1, xc[ks], aV21);
      }
      __syncthreads();   // end of phase: drains this phase's prefetch, frees other buf
    }
    // scores for this lane's batch row: reduce regs + lane>>4 groups
    float s1 = 0.f, s2 = 0.f;
#pragma unroll
    for (int r = 0; r < 4; ++r) {
      s1 += aQ0[r] * aK10[r] + aQ1[r] * aK11[r];
      s2 += aQ0[r] * aK20[r] + aQ1[r] * aK21[r];
    }
    s1 += __shfl_xor(s1, 16); s1 += __shfl_xor(s1, 32);
    s2 += __shfl_xor(s2, 16); s2 += __shfl_xor(s2, 32);
    s1 *= (1.0f / 32.0f);  s2 *= (1.0f / 32.0f);   // reference divides by d_k
    const float mx = fmaxf(s1, s2);
    const float e1 = __expf(s1 - mx), e2 = __expf(s2 - mx);
    const float a1 = e1 / (e1 + e2);
    const float a2 = 1.0f - a1;
#pragma unroll
    for (int r = 0; r < 4; ++r) {
      mo0[h][r] = (bf16_t)(a1 * aV10[r] + a2 * aV20[r]);
      mo1[h][r] = (bf16_t)(a1 * aV11[r] + a2 * aV21[r]);
    }
  }

  // ---- build out-proj B-frags in-register (PI pack makes this a concat) ----
  bf16x8 mfrag[NHEAD];
#pragma unroll
  for (int h = 0; h < NHEAD; ++h) {
    bf16x8 t;
    t[0] = mo0[h][0]; t[1] = mo0[h][1]; t[2] = mo0[h][2]; t[3] = mo0[h][3];
    t[4] = mo1[h][0]; t[5] = mo1[h][1]; t[6] = mo1[h][2]; t[7] = mo1[h][3];
    mfrag[h] = t;
  }

  // ---- output projection: 8 pipelined Wo phases (16 KB each) ----
  f32x4 acc[16];
#pragma unroll
  for (int jt = 0; jt < 16; ++jt) acc[jt] = f32x4{0.f, 0.f, 0.f, 0.f};

#pragma unroll
  for (int wp = 0; wp < 8; ++wp) {           // phase 16+wp, parity (16+wp)&1 = wp&1
    stage(17 + wp);
    bf16x8 mf = mfrag[wp];
    const char* pb = wbuf + (wp & 1) * 24576 + lane * 16;
#pragma unroll
    for (int jt = 0; jt < 16; ++jt) {
      bf16x8 wf = *(const bf16x8*)(pb + jt * 1024);
      acc[jt] = mfma16(wf, mf, acc[jt]);
    }
    __syncthreads();
  }

  // epilogue: bias + NT stores; lane writes 16B chunks of its own row
#pragma unroll
  for (int jt = 0; jt < 16; ++jt) {
    const int jj = jt * 16 + lg * 4;
    const float4 b4 = *(const float4*)(bo + jj);
    f32x4 o;
    o[0] = acc[jt][0] + b4.x;
    o[1] = acc[jt][1] + b4.y;
    o[2] = acc[jt][2] + b4.z;
    o[3] = acc[jt][3] + b4.w;
    __builtin_nontemporal_store(o, (f32x4*)(out + mrow * HID + jj));
  }
}

extern "C" void kernel_launch(void* const* d_in, const int* in_sizes, int n_in,
                              void* d_out, int out_size, void* d_ws, size_t ws_size,
                              hipStream_t stream) {
  (void)in_sizes; (void)n_in; (void)ws_size; (void)out_size;
  const float* fine   = (const float*)d_in[0];
  const float* coarse = (const float*)d_in[1];
  const float* motif  = (const float*)d_in[2];
  const float* Wq     = (const float*)d_in[3];
  const float* Wk     = (const float*)d_in[4];
  const float* Wv     = (const float*)d_in[5];
  const float* Wo     = (const float*)d_in[6];
  const float* bo     = (const float*)d_in[7];
  float* out          = (float*)d_out;
  bf16_t* wpk         = (bf16_t*)d_ws;

  pack_weights<<<128, 256, 0, stream>>>(Wq, Wk, Wv, Wo, wpk);
  fused_local_aug<<<B_TOT / BR, NTHR, 0, stream>>>(fine, coarse, motif, wpk, bo, out);
}

// Round 8
// 374.582 us; speedup vs baseline: 3.1740x; 3.1740x over previous
//
#include <hip/hip_runtime.h>

#define B_TOT 262144
#define HID   256
#define NHEAD 8
#define BR    64       // rows per block
#define NTHR  256      // 4 waves; wave owns 16 batch rows end-to-end

typedef __bf16 bf16_t;
typedef __attribute__((ext_vector_type(8))) __bf16 bf16x8;
typedef __attribute__((ext_vector_type(4))) __bf16 bf16x4;
typedef __attribute__((ext_vector_type(4))) float  f32x4;

// d_ws layout (bf16, fragment-ordered; byte = chunk*1024 + lane*16):
//   QKV: chunk = (h*8+ks)*6 + wi*2 + half   (wi: 0=q 1=k 2=v), chunk in [0,384)
//        element = W[h*32 + PI(lane&15,half)][ks*32 + (lane>>4)*8 .. +8]
//        PI(m,half) = (m>>2)*8 + half*4 + (m&3)
//        (permutation makes attention-mix C-frags == out-proj B-frags, no shuffles)
//   Wo:  chunk = 384 + ks*16 + jt, chunk in [384,512)
//        element = Wo[jt*16 + (lane&15)][ks*32 + (lane>>4)*8 .. +8]   (linear cols)
#define QKV_BYTES (384 * 1024)

static __device__ __forceinline__ f32x4 mfma16(bf16x8 a, bf16x8 b, f32x4 c) {
  return __builtin_amdgcn_mfma_f32_16x16x32_bf16(a, b, c, 0, 0, 0);
}

static __device__ __forceinline__ bf16x8 cvt8(float4 a, float4 b) {
  bf16x8 r;
  r[0] = (bf16_t)a.x; r[1] = (bf16_t)a.y; r[2] = (bf16_t)a.z; r[3] = (bf16_t)a.w;
  r[4] = (bf16_t)b.x; r[5] = (bf16_t)b.y; r[6] = (bf16_t)b.z; r[7] = (bf16_t)b.w;
  return r;
}

// opaque register pin: forbids rematerialization of the producing loads
static __device__ __forceinline__ bf16x8 pin8(bf16x8 v) {
  f32x4 t = __builtin_bit_cast(f32x4, v);
  asm volatile("" : "+v"(t));
  return __builtin_bit_cast(bf16x8, t);
}

// async global -> LDS, 16B per lane; lds dest must be linear (uniform base + lane*16)
typedef __attribute__((address_space(3))) void lds_void;
typedef __attribute__((address_space(1))) void gbl_void;
static __device__ __forceinline__ void gload_lds16(const void* g, void* l) {
  __builtin_amdgcn_global_load_lds((gbl_void*)g, (lds_void*)l, 16, 0, 0);
}

// ---- one-shot weight pack: f32 row-major -> bf16 fragment-ordered in ws ----
__global__ __launch_bounds__(256) void pack_weights(
    const float* __restrict__ Wq, const float* __restrict__ Wk,
    const float* __restrict__ Wv, const float* __restrict__ Wo,
    bf16_t* __restrict__ ws) {
  const int t     = blockIdx.x * 256 + threadIdx.x;   // 0..32767
  const int lane  = t & 63;
  const int chunk = t >> 6;                           // 0..511
  const int l15 = lane & 15, lg = lane >> 4;
  const float* src;
  int row, col;
  if (chunk < 384) {  // QKV: 64 (h,ks) pairs * 6 slots
    const int slot = chunk % 6;          // wi*2 + half
    const int hk   = chunk / 6;          // h*8 + ks
    const int wi = slot >> 1, half = slot & 1;
    const int h = hk >> 3, ks = hk & 7;
    src = (wi == 0) ? Wq : (wi == 1) ? Wk : Wv;
    row = h * 32 + (l15 >> 2) * 8 + half * 4 + (l15 & 3);   // PI permutation
    col = ks * 32 + lg * 8;
  } else {            // Wo: 8 ks * 16 jt, linear
    const int c  = chunk - 384;
    const int ks = c >> 4, jt = c & 15;
    src = Wo;
    row = jt * 16 + l15;
    col = ks * 32 + lg * 8;
  }
  const float* p = src + (size_t)row * HID + col;
  const float4 a = *(const float4*)p;
  const float4 b = *(const float4*)(p + 4);
  *(bf16x8*)(ws + (size_t)t * 8) = cvt8(a, b);
}

__global__ __launch_bounds__(NTHR, 2) void fused_local_aug(
    const float* __restrict__ fine, const float* __restrict__ coarse,
    const float* __restrict__ motif, const bf16_t* __restrict__ wpk,
    const float* __restrict__ bo, float* __restrict__ out) {
  // double-buffered W staging: 2 x 24 KB = 48 KB -> 2 blocks/CU co-resident
  __shared__ char wbuf[49152];

  const int tid  = threadIdx.x;
  const int lane = tid & 63;
  const int wave = tid >> 6;        // 0..3
  const int l15  = lane & 15;
  const int lg   = lane >> 4;       // 0..3
  const size_t row0 = (size_t)blockIdx.x * BR;
  const size_t mrow = row0 + wave * 16 + l15;   // this lane's batch row

  // phase table: ph 0..15 = (head h=ph>>1, half=ph&1), 24 KB each
  //              ph 16..23 = Wo ks-slot (ph-16), 16 KB each
  // phase ph reads wbuf[(ph&1)*24576]; stage(ph) prefetches into the same.
  auto stage = [&](int ph) {
    if (ph >= 24) return;
    char* dst = wbuf + (ph & 1) * 24576 + tid * 16;
    if (ph < 16) {
      const char* src = (const char*)wpk + (ph >> 1) * 49152 + (ph & 1) * 24576 + tid * 16;
#pragma unroll
      for (int i = 0; i < 6; ++i)
        gload_lds16(src + i * 4096, dst + i * 4096);
    } else {
      const char* src = (const char*)wpk + QKV_BYTES + (ph - 16) * 16384 + tid * 16;
#pragma unroll
      for (int i = 0; i < 4; ++i)
        gload_lds16(src + i * 4096, dst + i * 4096);
    }
  };

  stage(0);   // prefetch phase 0 under the X prologue

  // ---- preload this wave's 16 X rows into pinned bf16 register fragments ----
  bf16x8 xm[8], xf[8], xc[8];
  {
    const float* pm = motif  + mrow * HID + lg * 8;
    const float* pf = fine   + mrow * HID + lg * 8;
    const float* pc = coarse + mrow * HID + lg * 8;
#pragma unroll
    for (int s = 0; s < 8; ++s) {
      xm[s] = pin8(cvt8(*(const float4*)(pm + s * 32), *(const float4*)(pm + s * 32 + 4)));
      xf[s] = pin8(cvt8(*(const float4*)(pf + s * 32), *(const float4*)(pf + s * 32 + 4)));
      xc[s] = pin8(cvt8(*(const float4*)(pc + s * 32), *(const float4*)(pc + s * 32 + 4)));
    }
  }
  __syncthreads();   // phase 0 staged (vmcnt drained by all waves + barrier)

  // mid kept in registers: mo0[h][r] = feature h*32+lg*8+r, mo1[h][r] = +4
  bf16x4 mo0[NHEAD], mo1[NHEAD];

  // ---- head loop: 2 pipelined sub-phases per head, ONE barrier per phase ----
#pragma unroll
  for (int h = 0; h < NHEAD; ++h) {
    f32x4 aQ0{}, aQ1{}, aK10{}, aK11{}, aK20{}, aK21{}, aV10{}, aV11{}, aV20{}, aV21{};
#pragma unroll
    for (int half = 0; half < 2; ++half) {
      stage(2 * h + half + 1);               // issue next phase's loads FIRST
      const char* pb = wbuf + ((2 * h + half) & 1) * 24576 + lane * 16;
#pragma unroll
      for (int kk = 0; kk < 4; ++kk) {       // compute current buffer
        const int ks = half * 4 + kk;
        const char* p = pb + kk * 6144;
        bf16x8 q0 = *(const bf16x8*)(p);
        bf16x8 q1 = *(const bf16x8*)(p + 1024);
        bf16x8 k0 = *(const bf16x8*)(p + 2048);
        bf16x8 k1 = *(const bf16x8*)(p + 3072);
        bf16x8 v0 = *(const bf16x8*)(p + 4096);
        bf16x8 v1 = *(const bf16x8*)(p + 5120);
        aQ0  = mfma16(q0, xm[ks], aQ0);   aQ1  = mfma16(q1, xm[ks], aQ1);
        aK10 = mfma16(k0, xf[ks], aK10);  aK11 = mfma16(k1, xf[ks], aK11);
        aK20 = mfma16(k0, xc[ks], aK20);  aK21 = mfma16(k1, xc[ks], aK21);
        aV10 = mfma16(v0, xf[ks], aV10);  aV11 = mfma16(v1, xf[ks], aV11);
        aV20 = mfma16(v0, xc[ks], aV20);  aV21 = mfma16(v1, xc[ks], aV21);
      }
      __syncthreads();   // end of phase: drains prefetch, frees the other buffer
    }
    // scores for this lane's batch row: reduce regs + lane>>4 groups
    float s1 = 0.f, s2 = 0.f;
#pragma unroll
    for (int r = 0; r < 4; ++r) {
      s1 += aQ0[r] * aK10[r] + aQ1[r] * aK11[r];
      s2 += aQ0[r] * aK20[r] + aQ1[r] * aK21[r];
    }
    s1 += __shfl_xor(s1, 16); s1 += __shfl_xor(s1, 32);
    s2 += __shfl_xor(s2, 16); s2 += __shfl_xor(s2, 32);
    s1 *= (1.0f / 32.0f);  s2 *= (1.0f / 32.0f);   // reference divides by d_k
    const float mx = fmaxf(s1, s2);
    const float e1 = __expf(s1 - mx), e2 = __expf(s2 - mx);
    const float a1 = e1 / (e1 + e2);
    const float a2 = 1.0f - a1;
#pragma unroll
    for (int r = 0; r < 4; ++r) {
      mo0[h][r] = (bf16_t)(a1 * aV10[r] + a2 * aV20[r]);
      mo1[h][r] = (bf16_t)(a1 * aV11[r] + a2 * aV21[r]);
    }
  }

  // ---- build out-proj B-frags in-register (PI pack makes this a concat) ----
  bf16x8 mfrag[NHEAD];
#pragma unroll
  for (int h = 0; h < NHEAD; ++h) {
    bf16x8 t;
    t[0] = mo0[h][0]; t[1] = mo0[h][1]; t[2] = mo0[h][2]; t[3] = mo0[h][3];
    t[4] = mo1[h][0]; t[5] = mo1[h][1]; t[6] = mo1[h][2]; t[7] = mo1[h][3];
    mfrag[h] = t;
  }

  // ---- output projection: 8 pipelined Wo phases (16 KB each) ----
  f32x4 acc[16];
#pragma unroll
  for (int jt = 0; jt < 16; ++jt) acc[jt] = f32x4{0.f, 0.f, 0.f, 0.f};

#pragma unroll
  for (int wp = 0; wp < 8; ++wp) {           // phase 16+wp, parity = wp&1
    stage(17 + wp);                          // (ph16 was staged in last head phase)
    bf16x8 mf = mfrag[wp];
    const char* pb = wbuf + (wp & 1) * 24576 + lane * 16;
#pragma unroll
    for (int jt = 0; jt < 16; ++jt) {
      bf16x8 wf = *(const bf16x8*)(pb + jt * 1024);
      acc[jt] = mfma16(wf, mf, acc[jt]);
    }
    __syncthreads();
  }

  // epilogue: bias + NT stores; lane writes 16B chunks of its own full row
#pragma unroll
  for (int jt = 0; jt < 16; ++jt) {
    const int jj = jt * 16 + lg * 4;
    const float4 b4 = *(const float4*)(bo + jj);
    f32x4 o;
    o[0] = acc[jt][0] + b4.x;
    o[1] = acc[jt][1] + b4.y;
    o[2] = acc[jt][2] + b4.z;
    o[3] = acc[jt][3] + b4.w;
    __builtin_nontemporal_store(o, (f32x4*)(out + mrow * HID + jj));
  }
}

extern "C" void kernel_launch(void* const* d_in, const int* in_sizes, int n_in,
                              void* d_out, int out_size, void* d_ws, size_t ws_size,
                              hipStream_t stream) {
  (void)in_sizes; (void)n_in; (void)ws_size; (void)out_size;
  const float* fine   = (const float*)d_in[0];
  const float* coarse = (const float*)d_in[1];
  const float* motif  = (const float*)d_in[2];
  const float* Wq     = (const float*)d_in[3];
  const float* Wk     = (const float*)d_in[4];
  const float* Wv     = (const float*)d_in[5];
  const float* Wo     = (const float*)d_in[6];
  const float* bo     = (const float*)d_in[7];
  float* out          = (float*)d_out;
  bf16_t* wpk         = (bf16_t*)d_ws;

  pack_weights<<<128, 256, 0, stream>>>(Wq, Wk, Wv, Wo, wpk);
  fused_local_aug<<<B_TOT / BR, NTHR, 0, stream>>>(fine, coarse, motif, wpk, bo, out);
}